// Round 7
// baseline (268.300 us; speedup 1.0000x reference)
//
#include <hip/hip_runtime.h>

#define SDIM 128
#define LDIM 8192
#define BATCH 32

// ws: per batch b at b*65536: [0:32K) KT fp16 frag-major, [32K:64K) VT fp16.
//   frag entry = (m*8+ks)*64 + lane, 16 B each; content at lane=H*32+ln:
//   KT: keys[16ks+8H .. +7][32m+ln]   VT: values[16ks+8H .. +7][32m+ln]
// ksum fp32 at WS_KSUM_OFF + b*512: ksum[j] = sum_d keys[j][d]
#define WS_KV_STRIDE 65536
#define WS_KSUM_OFF (BATCH * WS_KV_STRIDE)

typedef __attribute__((ext_vector_type(8))) _Float16 half8;
typedef __attribute__((ext_vector_type(16))) float float16;

union H8U { half8 v; _Float16 h[8]; unsigned w[4]; };
union PU { _Float16 h[2]; unsigned u; };

static __device__ __forceinline__ float16 mfma_f16(half8 a, half8 b, float16 c) {
    return __builtin_amdgcn_mfma_f32_32x32x16_f16(a, b, c, 0, 0, 0);
}

// ---------------- prep: KT / VT fp16 frags + ksum ----------------
// grid = 288: blocks [0,256): frag blocks (b = blk>>3, which = (blk>>2)&1, m = blk&3)
//             blocks [256,288): ksum blocks (b = blk-256)
__global__ __launch_bounds__(256) void prep_kernel(
        const float* __restrict__ keys, const float* __restrict__ values,
        char* __restrict__ ws) {
    __shared__ float T[SDIM * 33];   // [c][r'] fp32, stride 33 (c in [0,128), r' in [0,32))
    const int blk = blockIdx.x;
    const int tid = threadIdx.x;

    if (blk < 256) {
        const int b = blk >> 3, which = (blk >> 2) & 1, m = blk & 3;
        const float* src = (which ? values : keys) + (size_t)b * SDIM * SDIM;

        // load columns [32m, 32m+32) of src for all 128 rows c (coalesced float4)
        #pragma unroll
        for (int j = 0; j < 4; ++j) {
            int lin = j * 256 + tid;          // 1024 float4s total
            int c = lin >> 3, f4 = lin & 7;   // 8 float4 per row-slice
            float4 v = *(const float4*)(src + c * SDIM + m * 32 + f4 * 4);
            T[c * 33 + f4 * 4 + 0] = v.x;
            T[c * 33 + f4 * 4 + 1] = v.y;
            T[c * 33 + f4 * 4 + 2] = v.z;
            T[c * 33 + f4 * 4 + 3] = v.w;
        }
        __syncthreads();

        // emit 512 entries for this m: entry = (m*8+ks)*64 + lane
        char* dst = ws + (size_t)b * WS_KV_STRIDE + (which ? 32768 : 0);
        #pragma unroll
        for (int j = 0; j < 2; ++j) {
            int e = j * 256 + tid;            // [0,512)
            int ks = e >> 6, lane = e & 63;
            int Hh = (lane >> 5) & 1, ln = lane & 31;
            int c0 = 16 * ks + 8 * Hh;
            H8U o;
            #pragma unroll
            for (int i = 0; i < 8; ++i)
                o.h[i] = (_Float16)T[(c0 + i) * 33 + ln];
            *(half8*)(dst + ((m * 8 + ks) * 64 + lane) * 16) = o.v;
        }
    } else {
        // ksum[j] = sum_d keys[b][j][d]
        const int b = blk - 256;
        const float* src = keys + (size_t)b * SDIM * SDIM;
        int row = tid >> 1, h = tid & 1;
        const float4* p = (const float4*)(src + row * SDIM + h * 64);
        float s = 0.f;
        #pragma unroll
        for (int k = 0; k < 16; ++k) { float4 v = p[k]; s += v.x + v.y + v.z + v.w; }
        s += __shfl_xor(s, 1, 64);
        if (h == 0)
            ((float*)(ws + WS_KSUM_OFF + b * 512))[row] = s;
    }
}

// ---------------- attn: 1-wave blocks for phase diversity ----------------
// grid = BATCH*256; block = 64 threads = 1 wave; each block owns 32 q-rows.
__global__ __launch_bounds__(64, 4) void attn_kernel(
        const float* __restrict__ q, const char* __restrict__ ws,
        float* __restrict__ out) {
    __shared__ char smQ[8192];      // this wave's 32 Q-rows, fp16 frags, swizzled
    __shared__ float qsum_s[32];
    const int blk = blockIdx.x;
    const int b = blk >> 8, t32 = blk & 255;     // 256 consecutive blocks share KV (L2)
    const int tid = threadIdx.x, lane = tid & 63;
    const int H = lane >> 5, ln = lane & 31;

    const char* wsb = ws + (size_t)b * WS_KV_STRIDE;
    const float* qblk = q + ((size_t)b * LDIM + t32 * 32) * SDIM;
    float* ob = out + ((size_t)b * LDIM + t32 * 32) * SDIM;

    const char* ktp = wsb;                           // KT frags (L1/L2)
    const char* vtp = wsb + 32768;                   // VT frags
    const int lo16 = lane * 16;

    // ---- Q staging: thread handles rows rb..rb+7, col chunk cc (8 floats) ----
    const int rb = (((tid >> 4) & 3) << 3);
    const int cc = tid & 15;
    {
        float4 bufA[4][2], bufB[4][2];
        #pragma unroll
        for (int it = 0; it < 4; ++it) {
            const float* p = qblk + (rb + it) * SDIM + cc * 8;
            bufA[it][0] = *(const float4*)p;
            bufA[it][1] = *(const float4*)(p + 4);
        }
        #pragma unroll
        for (int it = 0; it < 4; ++it) {
            const float* p = qblk + (rb + 4 + it) * SDIM + cc * 8;
            bufB[it][0] = *(const float4*)p;
            bufB[it][1] = *(const float4*)(p + 4);
        }
        #pragma unroll
        for (int g = 0; g < 2; ++g) {
            #pragma unroll
            for (int it2 = 0; it2 < 4; ++it2) {
                int row = rb + g * 4 + it2;
                float4 v0 = g ? bufB[it2][0] : bufA[it2][0];
                float4 v1 = g ? bufB[it2][1] : bufA[it2][1];
                float f[8] = {v0.x, v0.y, v0.z, v0.w, v1.x, v1.y, v1.z, v1.w};
                float s = f[0] + f[1] + f[2] + f[3] + f[4] + f[5] + f[6] + f[7];
                s += __shfl_xor(s, 1, 64);
                s += __shfl_xor(s, 2, 64);
                s += __shfl_xor(s, 4, 64);
                s += __shfl_xor(s, 8, 64);
                if ((tid & 15) == 0) qsum_s[row] = s;
                H8U hv;
                #pragma unroll
                for (int i = 0; i < 8; ++i) hv.h[i] = (_Float16)f[i];
                *(half8*)(smQ + row * 256 + ((cc ^ (row & 15)) * 16)) = hv.v;
            }
        }
    }
    // single wave: no barrier needed (compiler orders via lgkmcnt)

    const char* qrp = smQ + ln * 256;  // this lane's q-row frags

    // ---- Phase 1: S2^T = KT x Q^T, 2-deep KT prefetch ----
    half8 ah[2][4];
    #pragma unroll
    for (int m = 0; m < 4; ++m)
        ah[0][m] = *(const half8*)(ktp + (m * 8 + 0) * 1024 + lo16);
    #pragma unroll
    for (int m = 0; m < 4; ++m)
        ah[1][m] = *(const half8*)(ktp + (m * 8 + 1) * 1024 + lo16);

    float16 acc[4];
    #pragma unroll
    for (int m = 0; m < 4; ++m) acc[m] = (float16)(0.0f);

    #pragma unroll
    for (int ks = 0; ks < 8; ++ks) {
        const int cur = ks & 1;
        half8 bh = *(const half8*)(qrp + ((2 * ks + H) ^ (ln & 15)) * 16);
        #pragma unroll
        for (int m = 0; m < 4; ++m) acc[m] = mfma_f16(ah[cur][m], bh, acc[m]);
        if (ks < 6) {
            #pragma unroll
            for (int m = 0; m < 4; ++m)
                ah[cur][m] = *(const half8*)(ktp + (m * 8 + ks + 2) * 1024 + lo16);
        }
    }

    // ---- ksum pipeline (global, L1/L2-resident) + VT t=0 prefetch ----
    const float4* ksg = (const float4*)(ws + WS_KSUM_OFF + b * 512);
    float4 kk[2][4];
    #pragma unroll
    for (int g = 0; g < 4; ++g) kk[0][g] = ksg[g * 2 + H];

    half8 av[2][4];
    #pragma unroll
    for (int dm = 0; dm < 4; ++dm)
        av[0][dm] = *(const half8*)(vtp + (dm * 8) * 1024 + lo16);

    // ---- exact rank-1 term: acc[m][4g+i] += ksum[32m+8g+4H+i] * qsum[row] ----
    const float qs = qsum_s[ln];
    #pragma unroll
    for (int m = 0; m < 4; ++m) {
        const int cur = m & 1;
        if (m < 3) {
            #pragma unroll
            for (int g = 0; g < 4; ++g) kk[cur ^ 1][g] = ksg[(m + 1) * 8 + g * 2 + H];
        }
        #pragma unroll
        for (int g = 0; g < 4; ++g) {
            float4 k4 = kk[cur][g];
            acc[m][4 * g + 0] = fmaf(k4.x, qs, acc[m][4 * g + 0]);
            acc[m][4 * g + 1] = fmaf(k4.y, qs, acc[m][4 * g + 1]);
            acc[m][4 * g + 2] = fmaf(k4.z, qs, acc[m][4 * g + 2]);
            acc[m][4 * g + 3] = fmaf(k4.w, qs, acc[m][4 * g + 3]);
        }
    }

    // ---- softmax over j: 64 in-lane + partner half ----
    float mx = -1e30f;
    #pragma unroll
    for (int m = 0; m < 4; ++m)
        #pragma unroll
        for (int r = 0; r < 16; ++r) mx = fmaxf(mx, acc[m][r]);
    mx = fmaxf(mx, __shfl_xor(mx, 32, 64));
    float sum = 0.0f;
    #pragma unroll
    for (int m = 0; m < 4; ++m)
        #pragma unroll
        for (int r = 0; r < 16; ++r) {
            float e = __expf(acc[m][r] - mx);
            acc[m][r] = e;
            sum += e;
        }
    sum += __shfl_xor(sum, 32, 64);
    const float inv = 1.0f / sum;

    // pack P^T rows to fp16 pairs
    unsigned pk[4][8];
    #pragma unroll
    for (int m = 0; m < 4; ++m)
        #pragma unroll
        for (int rr = 0; rr < 8; ++rr) {
            PU pu;
            pu.h[0] = (_Float16)(acc[m][2 * rr] * inv);
            pu.h[1] = (_Float16)(acc[m][2 * rr + 1] * inv);
            pk[m][rr] = pu.u;
        }

    // VT t=1 prologue (acc just died into pk; regs free)
    #pragma unroll
    for (int dm = 0; dm < 4; ++dm)
        av[1][dm] = *(const half8*)(vtp + (dm * 8 + 1) * 1024 + lo16);

    // ---- Phase 2: out^T = VT x P^T, 2-deep VT prefetch ----
    float16 oacc[4];
    #pragma unroll
    for (int m = 0; m < 4; ++m) oacc[m] = (float16)(0.0f);

    #pragma unroll
    for (int t = 0; t < 8; ++t) {
        const int cur = t & 1;
        const int m = t >> 1;
        const int c = 4 * (t & 1);
        unsigned p0 = pk[m][c], p1 = pk[m][c + 1], p2 = pk[m][c + 2], p3 = pk[m][c + 3];
        unsigned a0 = H ? p2 : p0, a1 = H ? p3 : p1;
        unsigned s0 = H ? p0 : p2, s1 = H ? p1 : p3;
        unsigned r0 = (unsigned)__shfl_xor((int)s0, 32, 64);
        unsigned r1 = (unsigned)__shfl_xor((int)s1, 32, 64);
        H8U bf;
        bf.w[0] = H ? r0 : a0;
        bf.w[1] = H ? r1 : a1;
        bf.w[2] = H ? a0 : r0;
        bf.w[3] = H ? a1 : r1;
        #pragma unroll
        for (int dm = 0; dm < 4; ++dm)
            oacc[dm] = mfma_f16(av[cur][dm], bf.v, oacc[dm]);
        if (t < 6) {
            #pragma unroll
            for (int dm = 0; dm < 4; ++dm)
                av[cur][dm] = *(const half8*)(vtp + (dm * 8 + t + 2) * 1024 + lo16);
        }
    }

    // ---- epilogue: direct out^T C-layout stores (measured-best R3 form) ----
    #pragma unroll
    for (int dm = 0; dm < 4; ++dm)
        #pragma unroll
        for (int g = 0; g < 4; ++g) {
            float4 v = make_float4(oacc[dm][4 * g], oacc[dm][4 * g + 1],
                                   oacc[dm][4 * g + 2], oacc[dm][4 * g + 3]);
            *(float4*)(ob + ln * SDIM + dm * 32 + g * 8 + H * 4) = v;
        }
}

extern "C" void kernel_launch(void* const* d_in, const int* in_sizes, int n_in,
                              void* d_out, int out_size, void* d_ws, size_t ws_size,
                              hipStream_t stream) {
    const float* q    = (const float*)d_in[0];
    const float* keys = (const float*)d_in[1];
    const float* vals = (const float*)d_in[2];
    float* out = (float*)d_out;
    char*  ws  = (char*)d_ws;   // needs ~2.02 MB

    prep_kernel<<<BATCH * 8 + BATCH, 256, 0, stream>>>(keys, vals, ws);
    attn_kernel<<<BATCH * 256, 64, 0, stream>>>(q, ws, out);
}

// Round 8
// 260.018 us; speedup vs baseline: 1.0319x; 1.0319x over previous
//
#include <hip/hip_runtime.h>

#define SDIM 128
#define LDIM 8192
#define BATCH 32

// ws: per batch b at b*65536: [0:32K) KT fp16 frag-major, [32K:64K) VT fp16.
//   frag entry = (m*8+ks)*64 + lane, 16 B each; content at lane=H*32+ln:
//   KT: keys[16ks+8H .. +7][32m+ln]   VT: values[16ks+8H .. +7][32m+ln]
// ksum fp32 at WS_KSUM_OFF + b*512: ksum[j] = sum_d keys[j][d]
#define WS_KV_STRIDE 65536
#define WS_KSUM_OFF (BATCH * WS_KV_STRIDE)

typedef __attribute__((ext_vector_type(8))) _Float16 half8;
typedef __attribute__((ext_vector_type(16))) float float16;

union H8U { half8 v; _Float16 h[8]; unsigned w[4]; };
union PU { _Float16 h[2]; unsigned u; };

static __device__ __forceinline__ float16 mfma_f16(half8 a, half8 b, float16 c) {
    return __builtin_amdgcn_mfma_f32_32x32x16_f16(a, b, c, 0, 0, 0);
}

// ---------------- prep: KT / VT fp16 frags + ksum ----------------
// grid = 288: blocks [0,256): frag blocks (b = blk>>3, which = (blk>>2)&1, m = blk&3)
//             blocks [256,288): ksum blocks (b = blk-256)
__global__ __launch_bounds__(256) void prep_kernel(
        const float* __restrict__ keys, const float* __restrict__ values,
        char* __restrict__ ws) {
    __shared__ float T[SDIM * 33];   // [c][r'] fp32, stride 33 (c in [0,128), r' in [0,32))
    const int blk = blockIdx.x;
    const int tid = threadIdx.x;

    if (blk < 256) {
        const int b = blk >> 3, which = (blk >> 2) & 1, m = blk & 3;
        const float* src = (which ? values : keys) + (size_t)b * SDIM * SDIM;

        // load columns [32m, 32m+32) of src for all 128 rows c (coalesced float4)
        #pragma unroll
        for (int j = 0; j < 4; ++j) {
            int lin = j * 256 + tid;          // 1024 float4s total
            int c = lin >> 3, f4 = lin & 7;   // 8 float4 per row-slice
            float4 v = *(const float4*)(src + c * SDIM + m * 32 + f4 * 4);
            T[c * 33 + f4 * 4 + 0] = v.x;
            T[c * 33 + f4 * 4 + 1] = v.y;
            T[c * 33 + f4 * 4 + 2] = v.z;
            T[c * 33 + f4 * 4 + 3] = v.w;
        }
        __syncthreads();

        // emit 512 entries for this m: entry = (m*8+ks)*64 + lane
        char* dst = ws + (size_t)b * WS_KV_STRIDE + (which ? 32768 : 0);
        #pragma unroll
        for (int j = 0; j < 2; ++j) {
            int e = j * 256 + tid;            // [0,512)
            int ks = e >> 6, lane = e & 63;
            int Hh = (lane >> 5) & 1, ln = lane & 31;
            int c0 = 16 * ks + 8 * Hh;
            H8U o;
            #pragma unroll
            for (int i = 0; i < 8; ++i)
                o.h[i] = (_Float16)T[(c0 + i) * 33 + ln];
            *(half8*)(dst + ((m * 8 + ks) * 64 + lane) * 16) = o.v;
        }
    } else {
        // ksum[j] = sum_d keys[b][j][d]
        const int b = blk - 256;
        const float* src = keys + (size_t)b * SDIM * SDIM;
        int row = tid >> 1, h = tid & 1;
        const float4* p = (const float4*)(src + row * SDIM + h * 64);
        float s = 0.f;
        #pragma unroll
        for (int k = 0; k < 16; ++k) { float4 v = p[k]; s += v.x + v.y + v.z + v.w; }
        s += __shfl_xor(s, 1, 64);
        if (h == 0)
            ((float*)(ws + WS_KSUM_OFF + b * 512))[row] = s;
    }
}

// ---------------- attn: 1-wave blocks, 2-tile software pipeline ----------------
// grid = BATCH*128; block = 64 threads = 1 wave; each block owns 64 q-rows
// (two 32-row tiles). Tile t+1's Q loads issue under tile t's softmax+PV
// compute so HBM requests stay outstanding through the compute middle.
__global__ __launch_bounds__(64) void attn_kernel(
        const float* __restrict__ q, const char* __restrict__ ws,
        float* __restrict__ out) {
    __shared__ char smQ[8192];      // current tile's 32 Q-rows, fp16 frags, swizzled
    __shared__ float qsum_s[32];
    const int blk = blockIdx.x;
    const int b = blk >> 7, pair = blk & 127;    // 128 consecutive blocks share KV (L2)
    const int tid = threadIdx.x, lane = tid & 63;
    const int H = lane >> 5, ln = lane & 31;

    const char* wsb = ws + (size_t)b * WS_KV_STRIDE;
    const float* qblk = q + ((size_t)b * LDIM + pair * 64) * SDIM;
    float* obase = out + ((size_t)b * LDIM + pair * 64) * SDIM;

    const char* ktp = wsb;                           // KT frags (L1/L2)
    const char* vtp = wsb + 32768;                   // VT frags
    const int lo16 = lane * 16;
    const int rb = (((tid >> 4) & 3) << 3);          // this thread's row base (in tile)
    const int cc = tid & 15;                         // col chunk (8 floats)

    // ---- Q load buffers: reused for both tiles (the pipeline registers) ----
    float4 bufA[4][2], bufB[4][2];
    #pragma unroll
    for (int it = 0; it < 4; ++it) {
        const float* p = qblk + (rb + it) * SDIM + cc * 8;
        bufA[it][0] = *(const float4*)p;
        bufA[it][1] = *(const float4*)(p + 4);
    }
    #pragma unroll
    for (int it = 0; it < 4; ++it) {
        const float* p = qblk + (rb + 4 + it) * SDIM + cc * 8;
        bufB[it][0] = *(const float4*)p;
        bufB[it][1] = *(const float4*)(p + 4);
    }

    #pragma unroll
    for (int t = 0; t < 2; ++t) {
        // ---- frag-ify bufs -> smQ fp16 frags + qsum (waits on this tile's loads) ----
        #pragma unroll
        for (int g = 0; g < 2; ++g) {
            #pragma unroll
            for (int it2 = 0; it2 < 4; ++it2) {
                int row = rb + g * 4 + it2;
                float4 v0 = g ? bufB[it2][0] : bufA[it2][0];
                float4 v1 = g ? bufB[it2][1] : bufA[it2][1];
                float f[8] = {v0.x, v0.y, v0.z, v0.w, v1.x, v1.y, v1.z, v1.w};
                float s = f[0] + f[1] + f[2] + f[3] + f[4] + f[5] + f[6] + f[7];
                s += __shfl_xor(s, 1, 64);
                s += __shfl_xor(s, 2, 64);
                s += __shfl_xor(s, 4, 64);
                s += __shfl_xor(s, 8, 64);
                if ((tid & 15) == 0) qsum_s[row] = s;
                H8U hv;
                #pragma unroll
                for (int i = 0; i < 8; ++i) hv.h[i] = (_Float16)f[i];
                *(half8*)(smQ + row * 256 + ((cc ^ (row & 15)) * 16)) = hv.v;
            }
        }
        // single wave: lgkmcnt ordering suffices, no barrier

        const char* qrp = smQ + ln * 256;  // this lane's q-row frags

        // ---- Phase 1: S2^T = KT x Q^T, 2-deep KT prefetch ----
        half8 ah[2][4];
        #pragma unroll
        for (int m = 0; m < 4; ++m)
            ah[0][m] = *(const half8*)(ktp + (m * 8 + 0) * 1024 + lo16);
        #pragma unroll
        for (int m = 0; m < 4; ++m)
            ah[1][m] = *(const half8*)(ktp + (m * 8 + 1) * 1024 + lo16);

        float16 acc[4];
        #pragma unroll
        for (int m = 0; m < 4; ++m) acc[m] = (float16)(0.0f);

        #pragma unroll
        for (int ks = 0; ks < 8; ++ks) {
            const int cur = ks & 1;
            half8 bh = *(const half8*)(qrp + ((2 * ks + H) ^ (ln & 15)) * 16);
            #pragma unroll
            for (int m = 0; m < 4; ++m) acc[m] = mfma_f16(ah[cur][m], bh, acc[m]);
            if (ks < 6) {
                #pragma unroll
                for (int m = 0; m < 4; ++m)
                    ah[cur][m] = *(const half8*)(ktp + (m * 8 + ks + 2) * 1024 + lo16);
            }
        }

        // ---- ksum pipeline + VT t=0 prefetch ----
        const float4* ksg = (const float4*)(ws + WS_KSUM_OFF + b * 512);
        float4 kk[2][4];
        #pragma unroll
        for (int g = 0; g < 4; ++g) kk[0][g] = ksg[g * 2 + H];

        half8 av[2][4];
        #pragma unroll
        for (int dm = 0; dm < 4; ++dm)
            av[0][dm] = *(const half8*)(vtp + (dm * 8) * 1024 + lo16);

        // ---- exact rank-1 term ----
        const float qs = qsum_s[ln];
        #pragma unroll
        for (int m = 0; m < 4; ++m) {
            const int cur = m & 1;
            if (m < 3) {
                #pragma unroll
                for (int g = 0; g < 4; ++g) kk[cur ^ 1][g] = ksg[(m + 1) * 8 + g * 2 + H];
            }
            #pragma unroll
            for (int g = 0; g < 4; ++g) {
                float4 k4 = kk[cur][g];
                acc[m][4 * g + 0] = fmaf(k4.x, qs, acc[m][4 * g + 0]);
                acc[m][4 * g + 1] = fmaf(k4.y, qs, acc[m][4 * g + 1]);
                acc[m][4 * g + 2] = fmaf(k4.z, qs, acc[m][4 * g + 2]);
                acc[m][4 * g + 3] = fmaf(k4.w, qs, acc[m][4 * g + 3]);
            }
        }

        // ---- PIPELINE: issue next tile's Q loads; they fly under softmax+PV ----
        if (t == 0) {
            const float* qn = qblk + 32 * SDIM;
            #pragma unroll
            for (int it = 0; it < 4; ++it) {
                const float* p = qn + (rb + it) * SDIM + cc * 8;
                bufA[it][0] = *(const float4*)p;
                bufA[it][1] = *(const float4*)(p + 4);
            }
            #pragma unroll
            for (int it = 0; it < 4; ++it) {
                const float* p = qn + (rb + 4 + it) * SDIM + cc * 8;
                bufB[it][0] = *(const float4*)p;
                bufB[it][1] = *(const float4*)(p + 4);
            }
        }

        // ---- softmax over j ----
        float mx = -1e30f;
        #pragma unroll
        for (int m = 0; m < 4; ++m)
            #pragma unroll
            for (int r = 0; r < 16; ++r) mx = fmaxf(mx, acc[m][r]);
        mx = fmaxf(mx, __shfl_xor(mx, 32, 64));
        float sum = 0.0f;
        #pragma unroll
        for (int m = 0; m < 4; ++m)
            #pragma unroll
            for (int r = 0; r < 16; ++r) {
                float e = __expf(acc[m][r] - mx);
                acc[m][r] = e;
                sum += e;
            }
        sum += __shfl_xor(sum, 32, 64);
        const float inv = 1.0f / sum;

        // pack P^T rows to fp16 pairs
        unsigned pk[4][8];
        #pragma unroll
        for (int m = 0; m < 4; ++m)
            #pragma unroll
            for (int rr = 0; rr < 8; ++rr) {
                PU pu;
                pu.h[0] = (_Float16)(acc[m][2 * rr] * inv);
                pu.h[1] = (_Float16)(acc[m][2 * rr + 1] * inv);
                pk[m][rr] = pu.u;
            }

        // VT t=1 prologue
        #pragma unroll
        for (int dm = 0; dm < 4; ++dm)
            av[1][dm] = *(const half8*)(vtp + (dm * 8 + 1) * 1024 + lo16);

        // ---- Phase 2: out^T = VT x P^T, 2-deep VT prefetch ----
        float16 oacc[4];
        #pragma unroll
        for (int m = 0; m < 4; ++m) oacc[m] = (float16)(0.0f);

        #pragma unroll
        for (int tt = 0; tt < 8; ++tt) {
            const int cur = tt & 1;
            const int m = tt >> 1;
            const int c = 4 * (tt & 1);
            unsigned p0 = pk[m][c], p1 = pk[m][c + 1], p2 = pk[m][c + 2], p3 = pk[m][c + 3];
            unsigned a0 = H ? p2 : p0, a1 = H ? p3 : p1;
            unsigned s0 = H ? p0 : p2, s1 = H ? p1 : p3;
            unsigned r0 = (unsigned)__shfl_xor((int)s0, 32, 64);
            unsigned r1 = (unsigned)__shfl_xor((int)s1, 32, 64);
            H8U bf;
            bf.w[0] = H ? r0 : a0;
            bf.w[1] = H ? r1 : a1;
            bf.w[2] = H ? a0 : r0;
            bf.w[3] = H ? a1 : r1;
            #pragma unroll
            for (int dm = 0; dm < 4; ++dm)
                oacc[dm] = mfma_f16(av[cur][dm], bf.v, oacc[dm]);
            if (tt < 6) {
                #pragma unroll
                for (int dm = 0; dm < 4; ++dm)
                    av[cur][dm] = *(const half8*)(vtp + (dm * 8 + tt + 2) * 1024 + lo16);
            }
        }

        // ---- epilogue: direct out^T C-layout stores ----
        float* ob = obase + (t * 32) * SDIM;
        #pragma unroll
        for (int dm = 0; dm < 4; ++dm)
            #pragma unroll
            for (int g = 0; g < 4; ++g) {
                float4 v = make_float4(oacc[dm][4 * g], oacc[dm][4 * g + 1],
                                       oacc[dm][4 * g + 2], oacc[dm][4 * g + 3]);
                *(float4*)(ob + ln * SDIM + dm * 32 + g * 8 + H * 4) = v;
            }
    }
}

extern "C" void kernel_launch(void* const* d_in, const int* in_sizes, int n_in,
                              void* d_out, int out_size, void* d_ws, size_t ws_size,
                              hipStream_t stream) {
    const float* q    = (const float*)d_in[0];
    const float* keys = (const float*)d_in[1];
    const float* vals = (const float*)d_in[2];
    float* out = (float*)d_out;
    char*  ws  = (char*)d_ws;   // needs ~2.02 MB

    prep_kernel<<<BATCH * 8 + BATCH, 256, 0, stream>>>(keys, vals, ws);
    attn_kernel<<<BATCH * 128, 64, 0, stream>>>(q, ws, out);
}